// Round 1
// baseline (304.958 us; speedup 1.0000x reference)
//
#include <hip/hip_runtime.h>

typedef unsigned short ushort_t;
typedef unsigned int   uint_t;
typedef __attribute__((ext_vector_type(8))) short  short8;
typedef __attribute__((ext_vector_type(4))) float  float4v;
typedef __attribute__((ext_vector_type(4))) uint_t uint4v;

#define B_    16
#define CIN_  320
#define COUT_ 320
#define NLORA 50
#define R_    4

// workspace layout (bytes)
#define XPAD_ELEMS ((size_t)B_ * 66 * 66 * CIN_)   // bf16 NHWC padded x
#define WEFF_OFF   (XPAD_ELEMS * 2)                // 44,605,440 B (16B aligned)

__device__ __forceinline__ ushort_t bf16rne(float f) {
  uint_t u = __float_as_uint(f);
  u = (u + 0x7FFFu + ((u >> 16) & 1u)) >> 16;
  return (ushort_t)u;
}

// async global->LDS, 16B per lane; LDS dest = wave-uniform base + lane*16
__device__ __forceinline__ void gld16(const ushort_t* g, ushort_t* l) {
  __builtin_amdgcn_global_load_lds(
      (const __attribute__((address_space(1))) void*)g,
      (__attribute__((address_space(3))) void*)l,
      16, 0, 0);
}

// ---------------------------------------------------------------------------
// Kernel 0: zero only the border ring of x_pad (replaces 45 MB memset; the
// interior is fully overwritten by pad_convert, W_eff fully by merge_weights).
// Per b: rows 0,65 full + cols 0,65 of rows 1..64  (83,200 elems = 166 KB).
// ---------------------------------------------------------------------------
__global__ __launch_bounds__(1024)
void zero_borders(ushort_t* __restrict__ x_pad) {
  const int b = blockIdx.x;
  ushort_t* base = x_pad + (size_t)b * 66 * 66 * CIN_;
  const int tid = threadIdx.x;
  // rows 0 and 65: 2 * 66*320 elems = 2*2640 16B-granules
  for (int g = tid; g < 2 * 2640; g += 1024) {
    int r = (g >= 2640) ? 1 : 0;
    int off = (g - r * 2640) * 8;
    *(uint4v*)(base + (size_t)(r * 65) * 66 * CIN_ + off) = (uint4v)0u;
  }
  // cols 0 and 65, rows 1..64: 64*2*40 granules
  for (int g = tid; g < 64 * 2 * 40; g += 1024) {
    int c8 = g % 40;
    int t2 = g / 40;
    int col = (t2 & 1) * 65;
    int row = 1 + (t2 >> 1);
    *(uint4v*)(base + ((size_t)row * 66 + col) * CIN_ + c8 * 8) = (uint4v)0u;
  }
}

// ---------------------------------------------------------------------------
// Kernel 1: x [B][C][H][W] fp32  ->  x_pad [B][66][66][C] bf16 (interior only;
// borders pre-zeroed by zero_borders). LDS transpose for coalescing both sides.
// ---------------------------------------------------------------------------
__global__ __launch_bounds__(256)
void pad_convert(const float* __restrict__ x, ushort_t* __restrict__ x_pad) {
  __shared__ float t[64][65];
  const int cc  = blockIdx.x;   // channel chunk 0..4 (64 ch each)
  const int h   = blockIdx.y;   // 0..63
  const int b   = blockIdx.z;
  const int tid = threadIdx.x;
  #pragma unroll
  for (int it = 0; it < 16; ++it) {
    int idx = it * 256 + tid;
    int cl = idx >> 6, wl = idx & 63;
    t[cl][wl] = x[(((size_t)(b * CIN_ + cc * 64 + cl)) * 64 + h) * 64 + wl];
  }
  __syncthreads();
  #pragma unroll
  for (int it = 0; it < 8; ++it) {
    int flat = (it * 256 + tid) * 2;          // even: (wl, cl-pair)
    int wl = flat >> 6, cl = flat & 63;
    uint_t u0 = bf16rne(t[cl][wl]);
    uint_t u1 = bf16rne(t[cl + 1][wl]);
    *(uint_t*)(x_pad + (((size_t)(b * 66 + h + 1)) * 66 + (wl + 1)) * CIN_ + cc * 64 + cl)
        = u0 | (u1 << 16);
  }
}

// ---------------------------------------------------------------------------
// Kernel 2: merged per-sample weights
//   W_eff[b][tap][o][c] = bf16( conv_w[o][c][tap] + act * sum_r up[l][o][r]*down[l][r][c][tap] )
// ---------------------------------------------------------------------------
__global__ __launch_bounds__(320)
void merge_weights(const float* __restrict__ conv_w, const float* __restrict__ down_w,
                   const float* __restrict__ up_w,  const void* __restrict__ lora,
                   ushort_t* __restrict__ W_eff) {
  const int o = blockIdx.x;       // 0..319
  const int b = blockIdx.y;       // 0..15
  const int c = threadIdx.x;      // 0..319

  // int32 vs int64 lora_id detection (reads only the first 64 B, valid either way)
  const int* p32 = (const int*)lora;
  bool odd0 = true;
  #pragma unroll
  for (int i = 1; i < 16; i += 2) odd0 = odd0 && (p32[i] == 0);
  long long raw = odd0 ? ((const long long*)lora)[b] : (long long)p32[b];
  long long idx = (raw >= 0) ? (raw >> 2) : -(((-raw) + 3) >> 2);   // floor(raw/4)
  float act = (idx >= 0) ? 1.0f : 0.0f;                              // SCALE==1.0 folded
  int l = (int)(idx < 0 ? 0 : (idx > (NLORA - 1) ? (NLORA - 1) : idx));

  float up[R_];
  #pragma unroll
  for (int r = 0; r < R_; ++r)
    up[r] = up_w[((size_t)l * COUT_ + o) * R_ + r] * act;

  #pragma unroll
  for (int tap = 0; tap < 9; ++tap) {
    float v = conv_w[((size_t)o * CIN_ + c) * 9 + tap];
    #pragma unroll
    for (int r = 0; r < R_; ++r)
      v += up[r] * down_w[(((size_t)l * R_ + r) * CIN_ + c) * 9 + tap];
    W_eff[(((size_t)b * 9 + tap) * COUT_ + o) * CIN_ + c] = bf16rne(v);
  }
}

// ---------------------------------------------------------------------------
// Kernel 3: main implicit-GEMM conv, bf16 MFMA 16x16x32, fp32 accumulate.
// 512 thr (8 waves), tile: 8 output rows x 64 cols x 64 out-ch. Wave wv owns
// output row h0+wv (4 m-subs x 4 n-subs). K chunks of 32 ch x 9 taps.
// Double-buffered LDS (2 x 79,872 B), global_load_lds staging with
// PRE-SWIZZLED SOURCE addresses (LDS dest linear), raw s_barrier + counted
// s_waitcnt vmcnt(9): next chunk's loads stay in flight across barriers.
// XCD-bijective block swizzle: each XCD owns 2 contiguous batch images.
// ---------------------------------------------------------------------------
#define XS_GRAN_PAD 2688                 // real 2640 x-granules + tail pad
#define WT_GRAN     2304
#define BUF_BYTES   ((XS_GRAN_PAD + WT_GRAN) * 16)   // 79,872

__global__ __launch_bounds__(512, 2)
void conv_main(const ushort_t* __restrict__ x_pad, const ushort_t* __restrict__ W_eff,
               const float* __restrict__ conv_b, float* __restrict__ out) {
  __shared__ __align__(16) char smem[2 * BUF_BYTES];  // 159,744 B

  const int tid = threadIdx.x;
  const int lin = blockIdx.x;                   // 0..639
  const int wg  = (lin & 7) * 80 + (lin >> 3);  // 640 = 8 XCD * 80: bijective
  const int b   = wg / 40;
  const int rem = wg - b * 40;
  const int o0  = (rem >> 3) * 64;              // 0..4 -> out-ch chunk
  const int h0  = (rem & 7) * 8;                // 0..7 -> row tile

  const int wv = tid >> 6;                      // wave 0..7
  const int la = tid & 15;
  const int q  = (tid >> 4) & 3;                // k-quad within wave

  // per-thread staging source offsets (elements, c0 added per chunk).
  // x granule g -> (qq,hh,ww); content = logical quad (qq ^ (ww&3)) so the
  // LINEAR LDS deposit realizes the XOR-swizzled layout (pre-swizzled source).
  int xsrc[6];
  #pragma unroll
  for (int i = 0; i < 6; ++i) {
    int g = i * 512 + tid;
    if (g > 2639) g = 2639;                     // tail lanes -> dup (land in pad)
    int qq = g & 3, t = g >> 2;
    int hh = t / 66, ww = t - hh * 66;
    xsrc[i] = ((b * 66 + h0 + hh) * 66 + ww) * CIN_ + ((qq ^ (ww & 3)) * 8);
  }
  int wsrc[5];
  #pragma unroll
  for (int j = 0; j < 5; ++j) {
    int g = j * 512 + tid;
    if (g > 2303) g = 2303;
    int qq = g & 3, o = (g >> 2) & 63, tap = g >> 8;
    wsrc[j] = ((b * 9 + tap) * COUT_ + o0 + o) * CIN_ + ((qq ^ (o & 3)) * 8);
  }

  float4v acc[4][4];
  #pragma unroll
  for (int i = 0; i < 4; ++i)
    #pragma unroll
    for (int n = 0; n < 4; ++n) acc[i][n] = (float4v)0.0f;

  // per-wave gld16 counts: wv0,1:11  wv2,3:10  wv4..7:9  -> min = 9
  auto STAGE = [&](int sel, int c0) {
    ushort_t* xb = (ushort_t*)(smem + sel * BUF_BYTES);
    ushort_t* wb = xb + XS_GRAN_PAD * 8;
    #pragma unroll
    for (int i = 0; i < 5; ++i)
      gld16(x_pad + xsrc[i] + c0, xb + (i * 512 + wv * 64) * 8);
    if (wv < 2)
      gld16(x_pad + xsrc[5] + c0, xb + (5 * 512 + wv * 64) * 8);
    #pragma unroll
    for (int j = 0; j < 4; ++j)
      gld16(W_eff + wsrc[j] + c0, wb + (j * 512 + wv * 64) * 8);
    if (wv < 4)
      gld16(W_eff + wsrc[4] + c0, wb + (4 * 512 + wv * 64) * 8);
  };

  STAGE(0, 0);                      // prologue: chunk 0 in flight
  int cur = 0;
  for (int t = 0; t < 10; ++t) {
    asm volatile("" ::: "memory");
    __builtin_amdgcn_s_barrier();   // all waves done reading buf cur^1
    asm volatile("" ::: "memory");
    if (t < 9) STAGE(cur ^ 1, (t + 1) * 32);
    __builtin_amdgcn_sched_barrier(0);
    if (t < 9) asm volatile("s_waitcnt vmcnt(9)" ::: "memory");
    else       asm volatile("s_waitcnt vmcnt(0)" ::: "memory");
    __builtin_amdgcn_sched_barrier(0);
    __builtin_amdgcn_s_barrier();   // all waves' chunk-t deposits visible
    asm volatile("" ::: "memory");

    const ushort_t* xb = (const ushort_t*)(smem + cur * BUF_BYTES);
    const ushort_t* wb = xb + XS_GRAN_PAD * 8;
    #pragma unroll
    for (int tap = 0; tap < 9; ++tap) {
      const int kh = tap / 3, kw = tap - kh * 3;
      short8 bf[4];
      #pragma unroll
      for (int n = 0; n < 4; ++n) {
        int o = n * 16 + la;
        bf[n] = *(const short8*)(wb + ((tap * 64 + o) * 4 + (q ^ (o & 3))) * 8);
      }
      const int hh = wv + kh;
      #pragma unroll
      for (int i = 0; i < 4; ++i) {
        int ww = i * 16 + la + kw;
        short8 af = *(const short8*)(xb + ((hh * 66 + ww) * 4 + (q ^ (ww & 3))) * 8);
        #pragma unroll
        for (int n = 0; n < 4; ++n)
          acc[i][n] = __builtin_amdgcn_mfma_f32_16x16x32_bf16(af, bf[n], acc[i][n], 0, 0, 0);
      }
    }
    cur ^= 1;
  }

  // Epilogue: transpose C through LDS (two 32-channel halves), add bias,
  // coalesced float4 NCHW stores. m index = wv*64 + i*16 + q*4 + reg.
  float* lc = (float*)smem;   // [32][516] fp32
  #pragma unroll
  for (int half = 0; half < 2; ++half) {
    __syncthreads();
    #pragma unroll
    for (int nn = 0; nn < 2; ++nn) {
      const int nsub  = half * 2 + nn;
      const int n_loc = nn * 16 + la;
      #pragma unroll
      for (int i = 0; i < 4; ++i) {
        const int m = wv * 64 + i * 16 + q * 4;
        *(float4v*)(lc + n_loc * 516 + m) = acc[i][nsub];
      }
    }
    __syncthreads();
    for (int f = tid; f < 32 * 128; f += 512) {
      int n_loc = f >> 7;
      int m4 = (f & 127) * 4;          // 0..508 = row*64 + col
      int o = o0 + half * 32 + n_loc;
      float4v v = *(const float4v*)(lc + n_loc * 516 + m4);
      v += conv_b[o];
      *(float4v*)(out + ((size_t)(b * COUT_ + o) * 4096) + h0 * 64 + m4) = v;
    }
  }
}

// ---------------------------------------------------------------------------
extern "C" void kernel_launch(void* const* d_in, const int* in_sizes, int n_in,
                              void* d_out, int out_size, void* d_ws, size_t ws_size,
                              hipStream_t stream) {
  const float* x      = (const float*)d_in[0];
  const float* conv_w = (const float*)d_in[1];
  const float* conv_b = (const float*)d_in[2];
  const float* down_w = (const float*)d_in[3];
  const float* up_w   = (const float*)d_in[4];
  const void*  lora   = d_in[5];
  float* out = (float*)d_out;

  ushort_t* x_pad = (ushort_t*)d_ws;
  ushort_t* W_eff = (ushort_t*)((char*)d_ws + WEFF_OFF);

  zero_borders <<<dim3(16),        1024, 0, stream>>>(x_pad);
  pad_convert  <<<dim3(5, 64, 16), 256,  0, stream>>>(x, x_pad);
  merge_weights<<<dim3(320, 16),   320,  0, stream>>>(conv_w, down_w, up_w, lora, W_eff);
  conv_main    <<<dim3(640),       512,  0, stream>>>(x_pad, W_eff, conv_b, out);
}

// Round 2
// 295.545 us; speedup vs baseline: 1.0319x; 1.0319x over previous
//
#include <hip/hip_runtime.h>

typedef unsigned short ushort_t;
typedef unsigned int   uint_t;
typedef __attribute__((ext_vector_type(8))) short  short8;
typedef __attribute__((ext_vector_type(4))) float  float4v;
typedef __attribute__((ext_vector_type(4))) uint_t uint4v;

#define B_    16
#define CIN_  320
#define COUT_ 320
#define NLORA 50
#define R_    4
#define NCH   10                       // channel chunks of 32

// x_pad: [B][10][66][66][32] bf16 ; W_eff: [B][10][9][320][32] bf16
#define XCHUNK (66*66*32)              // 139,392 elems per (b,cc)
#define WCHUNK (9*COUT_*32)            // 92,160 elems per (b,cc)
#define XPAD_ELEMS ((size_t)B_ * NCH * XCHUNK)
#define WEFF_OFF   (XPAD_ELEMS * 2)    // bytes

__device__ __forceinline__ ushort_t bf16rne(float f) {
  uint_t u = __float_as_uint(f);
  u = (u + 0x7FFFu + ((u >> 16) & 1u)) >> 16;
  return (ushort_t)u;
}

__device__ __forceinline__ void gld16(const ushort_t* g, ushort_t* l) {
  __builtin_amdgcn_global_load_lds(
      (const __attribute__((address_space(1))) void*)g,
      (__attribute__((address_space(3))) void*)l,
      16, 0, 0);
}

// ---------------------------------------------------------------------------
// Kernel 1: x [B][C][H][W] fp32 -> x_pad [B][C/32][66][66][32] bf16.
// LDS transpose for coalescing both sides. Blocks with h==0 also zero the
// border ring of their two 32-ch chunks (replaces the old zero kernel/memset).
// ---------------------------------------------------------------------------
__global__ __launch_bounds__(256)
void pad_convert(const float* __restrict__ x, ushort_t* __restrict__ x_pad) {
  __shared__ float t[64][65];
  const int cc  = blockIdx.x;   // 64-ch group 0..4
  const int h   = blockIdx.y;   // 0..63
  const int b   = blockIdx.z;
  const int tid = threadIdx.x;
  #pragma unroll
  for (int it = 0; it < 16; ++it) {
    int idx = it * 256 + tid;
    int cl = idx >> 6, wl = idx & 63;
    t[cl][wl] = x[(((size_t)(b * CIN_ + cc * 64 + cl)) * 64 + h) * 64 + wl];
  }
  __syncthreads();
  #pragma unroll
  for (int it = 0; it < 8; ++it) {
    int flat = (it * 256 + tid) * 2;          // (wl, even cl pair)
    int wl = flat >> 6, cl = flat & 63;
    uint_t u0 = bf16rne(t[cl][wl]);
    uint_t u1 = bf16rne(t[cl + 1][wl]);
    int chunk = cc * 2 + (cl >> 5);
    *(uint_t*)(x_pad + (((size_t)(b * NCH + chunk) * 66 + (h + 1)) * 66 + (wl + 1)) * 32
               + (cl & 31)) = u0 | (u1 << 16);
  }
  if (h == 0) {
    #pragma unroll
    for (int s = 0; s < 2; ++s) {
      ushort_t* base = x_pad + (size_t)(b * NCH + cc * 2 + s) * XCHUNK;
      // rows 0 and 65 (66 cols x 4 granules x 2 rows)
      for (int g = tid; g < 528; g += 256) {
        int r = (g >= 264) ? 1 : 0;
        int g2 = g - r * 264;
        int col = g2 >> 2, qg = g2 & 3;
        *(uint4v*)(base + ((size_t)(r * 65) * 66 + col) * 32 + qg * 8) = (uint4v)0u;
      }
      // cols 0 and 65, rows 1..64
      for (int g = tid; g < 512; g += 256) {
        int row = 1 + (g >> 3);
        int col = ((g >> 2) & 1) * 65;
        int qg  = g & 3;
        *(uint4v*)(base + ((size_t)row * 66 + col) * 32 + qg * 8) = (uint4v)0u;
      }
    }
  }
}

// ---------------------------------------------------------------------------
// Kernel 2: merged per-sample weights into chunked layout
//   W_eff[b][c/32][tap][o][c%32] = bf16(conv_w + act * sum_r up*down)
// ---------------------------------------------------------------------------
__global__ __launch_bounds__(320)
void merge_weights(const float* __restrict__ conv_w, const float* __restrict__ down_w,
                   const float* __restrict__ up_w,  const void* __restrict__ lora,
                   ushort_t* __restrict__ W_eff) {
  const int o = blockIdx.x;       // 0..319
  const int b = blockIdx.y;       // 0..15
  const int c = threadIdx.x;      // 0..319

  const int* p32 = (const int*)lora;
  bool odd0 = true;
  #pragma unroll
  for (int i = 1; i < 16; i += 2) odd0 = odd0 && (p32[i] == 0);
  long long raw = odd0 ? ((const long long*)lora)[b] : (long long)p32[b];
  long long idx = (raw >= 0) ? (raw >> 2) : -(((-raw) + 3) >> 2);   // floor(raw/4)
  float act = (idx >= 0) ? 1.0f : 0.0f;                              // SCALE==1.0 folded
  int l = (int)(idx < 0 ? 0 : (idx > (NLORA - 1) ? (NLORA - 1) : idx));

  float up[R_];
  #pragma unroll
  for (int r = 0; r < R_; ++r)
    up[r] = up_w[((size_t)l * COUT_ + o) * R_ + r] * act;

  const size_t wb = (size_t)(b * NCH + (c >> 5)) * 9;
  #pragma unroll
  for (int tap = 0; tap < 9; ++tap) {
    float v = conv_w[((size_t)o * CIN_ + c) * 9 + tap];
    #pragma unroll
    for (int r = 0; r < R_; ++r)
      v += up[r] * down_w[(((size_t)l * R_ + r) * CIN_ + c) * 9 + tap];
    W_eff[((wb + tap) * COUT_ + o) * 32 + (c & 31)] = bf16rne(v);
  }
}

// ---------------------------------------------------------------------------
// Kernel 3: implicit-GEMM conv, bf16 MFMA 16x16x32, fp32 accumulate.
// 512 thr (8 waves). Tile: 8 rows x 32 cols x 32 out-ch; wave wv = row h0+wv,
// 2 m-subs x 2 n-subs. Staging flattened to exactly 2560 x 16B granules
// (= 5 gld16 per thread, all waves uniform -> exact vmcnt(5)).
// LDS: 2 x 40,960 B double buffer = 81,920 -> EXACTLY 2 blocks/CU, so
// barriers/epilogue/staging of one block overlap compute of the other.
// Grid: 2560 blocks = 10/CU uniform; XCD-bijective swizzle, W-slice-major.
// ---------------------------------------------------------------------------
#define XG    1360                 // 10 rows * 34 cols * 4 quads
#define XGP   1408                 // padded to wave boundary
#define WG    1152                 // 9 taps * 32 o * 4 quads
#define TOTG  2560                 // XGP + WG  (= 5 * 512)
#define BUF_B (TOTG * 16)          // 40,960 B

__global__ __launch_bounds__(512, 4)
void conv_main(const ushort_t* __restrict__ x_pad, const ushort_t* __restrict__ W_eff,
               const float* __restrict__ conv_b, float* __restrict__ out) {
  __shared__ __align__(16) char smem[2 * BUF_B];   // 81,920 B

  const int tid = threadIdx.x;
  const int lin = blockIdx.x;                      // 0..2559
  const int wg  = (lin & 7) * 320 + (lin >> 3);    // XCD-bijective
  const int b   = wg / 160;
  const int rem = wg - b * 160;
  const int o0  = (rem >> 4) * 32;                 // o-chunk (outer: W reuse)
  const int hw  = rem & 15;
  const int h0  = (hw & 7) * 8;
  const int w0  = (hw >> 3) * 32;

  const int wv = tid >> 6;
  const int la = tid & 15;
  const int q  = (tid >> 4) & 3;

  // per-round per-thread staging source (advances by step each chunk)
  const ushort_t* psrc[5];
  int step[5];
  #pragma unroll
  for (int r = 0; r < 5; ++r) {
    int g = r * 512 + tid;
    if (g < XGP) {
      int gx = (g < XG) ? g : (XG - 1);            // tail dups land in LDS pad
      int qq = gx & 3, t = gx >> 2;
      int hh = t / 34, ww = t - hh * 34;
      psrc[r] = x_pad + (size_t)b * NCH * XCHUNK
              + (((h0 + hh) * 66 + (w0 + ww)) * 32 + qq * 8);
      step[r] = XCHUNK;
    } else {
      int gw = g - XGP;
      int qq = gw & 3, t2 = gw >> 2;
      int o = t2 & 31, tap = t2 >> 5;
      psrc[r] = W_eff + (size_t)b * NCH * WCHUNK
              + ((tap * COUT_ + o0 + o) * 32 + qq * 8);
      step[r] = WCHUNK;
    }
  }

  float4v acc[2][2];
  #pragma unroll
  for (int i = 0; i < 2; ++i)
    #pragma unroll
    for (int n = 0; n < 2; ++n) acc[i][n] = (float4v)0.0f;

  auto STAGE = [&](int sel) {
    ushort_t* bufb = (ushort_t*)(smem + sel * BUF_B);
    #pragma unroll
    for (int r = 0; r < 5; ++r) {
      gld16(psrc[r], bufb + (r * 512 + wv * 64) * 8);
      psrc[r] += step[r];
    }
  };

  STAGE(0);                          // chunk 0 in flight
  int cur = 0;
  for (int t = 0; t < NCH; ++t) {
    asm volatile("" ::: "memory");
    __builtin_amdgcn_s_barrier();    // all waves done reading buf cur^1
    asm volatile("" ::: "memory");
    if (t < NCH - 1) STAGE(cur ^ 1);
    __builtin_amdgcn_sched_barrier(0);
    if (t < NCH - 1) asm volatile("s_waitcnt vmcnt(5)" ::: "memory");
    else             asm volatile("s_waitcnt vmcnt(0)" ::: "memory");
    __builtin_amdgcn_sched_barrier(0);
    __builtin_amdgcn_s_barrier();    // chunk t fully deposited (all waves)
    asm volatile("" ::: "memory");

    const ushort_t* xb = (const ushort_t*)(smem + cur * BUF_B);
    const ushort_t* wb = xb + XGP * 8;
    #pragma unroll
    for (int tap = 0; tap < 9; ++tap) {
      const int kh = tap / 3, kw = tap - kh * 3;
      short8 bf0 = *(const short8*)(wb + ((tap * 32 +      la) * 4 + q) * 8);
      short8 bf1 = *(const short8*)(wb + ((tap * 32 + 16 + la) * 4 + q) * 8);
      const int hh = wv + kh;
      #pragma unroll
      for (int i = 0; i < 2; ++i) {
        short8 af = *(const short8*)(xb + ((hh * 34 + i * 16 + la + kw) * 4 + q) * 8);
        acc[i][0] = __builtin_amdgcn_mfma_f32_16x16x32_bf16(af, bf0, acc[i][0], 0, 0, 0);
        acc[i][1] = __builtin_amdgcn_mfma_f32_16x16x32_bf16(af, bf1, acc[i][1], 0, 0, 0);
      }
    }
    cur ^= 1;
  }

  // Epilogue: transpose C through LDS, add bias, coalesced float4 NCHW stores.
  __syncthreads();
  float* lc = (float*)smem;          // [32][260] fp32 = 33,280 B
  #pragma unroll
  for (int n = 0; n < 2; ++n) {
    const int n_loc = n * 16 + la;
    #pragma unroll
    for (int i = 0; i < 2; ++i)
      *(float4v*)(lc + n_loc * 260 + wv * 32 + i * 16 + q * 4) = acc[i][n];
  }
  __syncthreads();
  const size_t ob = ((size_t)(b * COUT_ + o0)) * 4096 + h0 * 64 + w0;
  for (int f = tid; f < 32 * 64; f += 512) {
    int n_loc = f >> 6;
    int m4 = (f & 63) * 4;
    int row = m4 >> 5, col = m4 & 31;
    float4v v = *(const float4v*)(lc + n_loc * 260 + m4);
    v += conv_b[o0 + n_loc];
    *(float4v*)(out + ob + (size_t)n_loc * 4096 + row * 64 + col) = v;
  }
}

// ---------------------------------------------------------------------------
extern "C" void kernel_launch(void* const* d_in, const int* in_sizes, int n_in,
                              void* d_out, int out_size, void* d_ws, size_t ws_size,
                              hipStream_t stream) {
  const float* x      = (const float*)d_in[0];
  const float* conv_w = (const float*)d_in[1];
  const float* conv_b = (const float*)d_in[2];
  const float* down_w = (const float*)d_in[3];
  const float* up_w   = (const float*)d_in[4];
  const void*  lora   = d_in[5];
  float* out = (float*)d_out;

  ushort_t* x_pad = (ushort_t*)d_ws;
  ushort_t* W_eff = (ushort_t*)((char*)d_ws + WEFF_OFF);

  pad_convert  <<<dim3(5, 64, 16), 256, 0, stream>>>(x, x_pad);
  merge_weights<<<dim3(320, 16),   320, 0, stream>>>(conv_w, down_w, up_w, lora, W_eff);
  conv_main    <<<dim3(2560),      512, 0, stream>>>(x_pad, W_eff, conv_b, out);
}